// Round 4
// baseline (1332.430 us; speedup 1.0000x reference)
//
#include <hip/hip_runtime.h>
#include <hip/hip_bf16.h>
#include <cfloat>
#include <cmath>

// Problem constants
#define NN 16384
#define H 4
#define D 64
#define B 512
#define KNBR 8            // neighbors kept per side
#define NC 16             // node chunks
#define CHUNK (NN / NC)   // 1024 nodes per chunk
#define NQ (2 * B)        // 1024 queries (src then dst)

typedef __attribute__((ext_vector_type(8))) short bf16x8;   // 8 bf16 = 4 VGPRs
typedef __attribute__((ext_vector_type(4))) float f32x4;
typedef unsigned long long ull;

static __device__ __forceinline__ ushort f2bf(float v) {
    __hip_bfloat16 b = __float2bfloat16(v);
    return *(ushort*)&b;
}

// ---------------------------------------------------------------- kernel 1
// pn2h[h*N+n] = |pos[n,h,:]|^2 (exact fp32); posb[h][n][d] = bf16(pos[n,h,d])
__global__ __launch_bounds__(256) void prep_pos(const float* __restrict__ pos,
                                                ushort* __restrict__ posb,
                                                float* __restrict__ pn2h) {
    int i = blockIdx.x * 256 + threadIdx.x;       // i = h*NN + n
    if (i >= NN * H) return;
    int h = i / NN, n = i % NN;
    const float* src = pos + ((size_t)n * H + h) * D;
    ushort* dst = posb + (size_t)i * D;
    float s = 0.f;
#pragma unroll
    for (int d = 0; d < D; d += 4) {
        float4 v = *(const float4*)(src + d);
        s += v.x * v.x + v.y * v.y + v.z * v.z + v.w * v.w;
        ushort4 u; u.x = f2bf(v.x); u.y = f2bf(v.y); u.z = f2bf(v.z); u.w = f2bf(v.w);
        *(ushort4*)(dst + d) = u;
    }
    pn2h[i] = s;
}

// ---------------------------------------------------------------- kernel 2
// MFMA distance tiles + fused per-chunk top-8 (packed u64 = d2bits<<32 | node).
// grid = (NQ/16, H, NC), block = 64 (one wave).
// Per block: 16 queries x 1024 nodes, 64 col-tiles in 16 groups of 4.
// A-fragments gathered directly from posb via edge ids (no staged qb).
// Hot path: float gate vs cached 8th-best; packed u64 only on rare insert.
__global__ __launch_bounds__(64, 3) void knn_mfma(const ushort* __restrict__ posb,
                                                  const float* __restrict__ pn2h,
                                                  const int* __restrict__ edges,
                                                  ull* __restrict__ part) {
    const int lane = threadIdx.x;
    const int qt = blockIdx.x;        // query tile (16 queries)
    const int h  = blockIdx.y;
    const int c  = blockIdx.z;        // node chunk (1024 nodes)
    const int col  = lane & 15;
    const int quad = lane >> 4;
    const int n0 = c * CHUNK;

    // my column's query node; A fragments from its pos row
    const int nodeq = edges[qt * 16 + col];
    const ushort* qrow = posb + ((size_t)h * NN + nodeq) * D + quad * 8;
    const bf16x8 a0 = *(const bf16x8*)qrow;
    const bf16x8 a1 = *(const bf16x8*)(qrow + 32);
    const float myqn2 = pn2h[(size_t)h * NN + nodeq];

    // query ids + |q|^2 for my quad's 4 rows, via shuffle from col-lanes
    int qn[4]; float qn2[4];
#pragma unroll
    for (int r = 0; r < 4; ++r) {
        qn[r]  = __shfl(nodeq, quad * 4 + r);
        qn2[r] = __shfl(myqn2, quad * 4 + r);
    }

    ull lst[4][KNBR];
    float g8[4];                       // float d2 of current 8th-best per row
#pragma unroll
    for (int r = 0; r < 4; ++r) {
        g8[r] = FLT_MAX;
#pragma unroll
        for (int j = 0; j < KNBR; ++j) lst[r][j] = ~0ull;
    }

    const ushort* prow = posb + ((size_t)h * NN + n0 + col) * D + quad * 8;
    const float* p2base = pn2h + (size_t)h * NN + n0 + col;

    for (int g = 0; g < 16; ++g) {
        bf16x8 b0[4], b1[4];
#pragma unroll
        for (int u = 0; u < 4; ++u) {
            const ushort* pr = prow + (size_t)(g * 4 + u) * 16 * D;
            b0[u] = *(const bf16x8*)pr;
            b1[u] = *(const bf16x8*)(pr + 32);
        }
        f32x4 acc[4];
#pragma unroll
        for (int u = 0; u < 4; ++u) {
            f32x4 z = {0.f, 0.f, 0.f, 0.f};
            z = __builtin_amdgcn_mfma_f32_16x16x32_bf16(a0, b0[u], z, 0, 0, 0);
            acc[u] = __builtin_amdgcn_mfma_f32_16x16x32_bf16(a1, b1[u], z, 0, 0, 0);
        }
        float p2[4];
#pragma unroll
        for (int u = 0; u < 4; ++u) p2[u] = p2base[(g * 4 + u) * 16];

#pragma unroll
        for (int u = 0; u < 4; ++u) {
            const int node = n0 + (g * 4 + u) * 16 + col;
#pragma unroll
            for (int r = 0; r < 4; ++r) {
                float d2 = fmaxf(fmaf(-2.f, acc[u][r], p2[u] + qn2[r]), 0.f);
                if (d2 < g8[r] && node != qn[r]) {   // rare insert path
                    ull cc = (((ull)__float_as_uint(d2)) << 32) | (unsigned)node;
#pragma unroll
                    for (int j = 0; j < KNBR; ++j) {
                        if (cc < lst[r][j]) { ull t = lst[r][j]; lst[r][j] = cc; cc = t; }
                    }
                    unsigned hw = (unsigned)(lst[r][KNBR - 1] >> 32);
                    g8[r] = (hw == 0xFFFFFFFFu) ? FLT_MAX : __uint_as_float(hw);
                }
            }
        }
    }

    // 16-lane pop-merge per query row (4 rows in parallel across quads).
    // Candidates unique (node id in low bits) -> equality identifies winner.
#pragma unroll
    for (int r = 0; r < 4; ++r) {
        const int pq = qt * 16 + quad * 4 + r;
        const size_t obase = (((size_t)pq * H + h) * NC + c) * KNBR;
        for (int s = 0; s < KNBR; ++s) {
            ull v = lst[r][0];
#pragma unroll
            for (int off = 1; off < 16; off <<= 1) {
                ull v2 = __shfl_xor(v, off);
                v = v2 < v ? v2 : v;
            }
            if (col == s) part[obase + s] = v;
            if (lst[r][0] == v) {
#pragma unroll
                for (int j = 0; j < KNBR - 1; ++j) lst[r][j] = lst[r][j + 1];
                lst[r][KNBR - 1] = ~0ull;
            }
        }
    }
}

// ---------------------------------------------------------------- kernel 3
// Merge 16 chunks x 8 = 128 packed candidates per (q,h) -> global top-8.
// grid = NQ*H, block = 64; lane holds 2 candidates as a sorted pair.
__global__ __launch_bounds__(64) void knn_merge(const ull* __restrict__ part,
                                                float* __restrict__ knn_d,
                                                int* __restrict__ knn_i) {
    const int lane = threadIdx.x;
    const int qh = blockIdx.x;              // q*H + h
    const size_t base = (size_t)qh * (NC * KNBR);
    ull v0 = part[base + lane];
    ull v1 = part[base + 64 + lane];
    ull lo = v0 < v1 ? v0 : v1;
    ull hi = v0 < v1 ? v1 : v0;
    for (int s = 0; s < KNBR; ++s) {
        ull m = lo;
#pragma unroll
        for (int off = 1; off < 64; off <<= 1) {
            ull m2 = __shfl_xor(m, off);
            m = m2 < m ? m2 : m;
        }
        if (lane == 0) {
            float d2 = __uint_as_float((unsigned)(m >> 32));
            knn_d[(size_t)qh * KNBR + s] = sqrtf(fmaxf(d2, 0.f));
            knn_i[(size_t)qh * KNBR + s] = (int)(unsigned)(m & 0xFFFFFFFFu);
        }
        if (lo == m) { lo = hi; hi = ~0ull; }
    }
}

// ---------------------------------------------------------------- kernel 4
// Per-edge logits + softmax(+8 sentinels dist=1, logit=0) + sigmoid(mean_h).
// grid = B, block = 64: lane = h*16 + t, t<8: src side, t>=8: dst side
__global__ __launch_bounds__(64) void finalize(const float* __restrict__ pos,
                                               const float* __restrict__ grads,
                                               const float* __restrict__ adj,
                                               const float* __restrict__ label_w,
                                               const int* __restrict__ edges,
                                               const float* __restrict__ knn_d,
                                               const int* __restrict__ knn_i,
                                               float* __restrict__ out) {
    const int b = blockIdx.x;
    const int lane = threadIdx.x;
    const int h = lane >> 4;
    const int t = lane & 15;
    const int sb = edges[b];
    const int db = edges[B + b];
    const float lw = label_w[0];

    int q, qn, gn;
    if (t < KNBR) { q = b;     qn = sb; gn = db; }   // src side: grads at dst
    else          { q = B + b; qn = db; gn = sb; }   // dst side: grads at src
    const int k = t & 7;
    const size_t kk = ((size_t)q * H + h) * KNBR + k;
    const int j = knn_i[kk];
    const float dist = knn_d[kk];
    const size_t adj_idx = (t < KNBR) ? ((size_t)j * NN + db) : ((size_t)sb * NN + j);

    const float4* pq4 = (const float4*)(pos + ((size_t)qn * H + h) * D);
    const float4* pj4 = (const float4*)(pos + ((size_t)j * H + h) * D);
    const float4* g4  = (const float4*)(grads + ((size_t)gn * H + h) * D);
    float contrib = 0.f;
#pragma unroll
    for (int d = 0; d < D / 4; ++d) {
        float4 a = pq4[d], p = pj4[d], g = g4[d];
        contrib = fmaf(a.x - p.x, g.x, contrib);
        contrib = fmaf(a.y - p.y, g.y, contrib);
        contrib = fmaf(a.z - p.z, g.z, contrib);
        contrib = fmaf(a.w - p.w, g.w, contrib);
    }
    float logit = fmaf(lw, adj[adj_idx], contrib);

    // softmax over 24 entries (16 real + 8 sentinels at dist 1.0, logit 0)
    float dmin = dist;
#pragma unroll
    for (int off = 1; off < 16; off <<= 1) dmin = fminf(dmin, __shfl_xor(dmin, off));
    dmin = fminf(dmin, 1.0f);
    float e = expf(dmin - dist);
    float num = e * logit;
    float den = e;
#pragma unroll
    for (int off = 1; off < 16; off <<= 1) {
        num += __shfl_xor(num, off);
        den += __shfl_xor(den, off);
    }
    den += 8.f * expf(dmin - 1.0f);
    float val = num / den;

#pragma unroll
    for (int off = 1; off < 64; off <<= 1) val += __shfl_xor(val, off);
    if (lane == 0) {
        float m = val * (1.f / 64.f);
        out[b] = 1.f / (1.f + expf(-m));
    }
}

// ----------------------------------------------------------------
extern "C" void kernel_launch(void* const* d_in, const int* in_sizes, int n_in,
                              void* d_out, int out_size, void* d_ws, size_t ws_size,
                              hipStream_t stream) {
    const float* pos     = (const float*)d_in[0];
    const float* grads   = (const float*)d_in[1];
    const float* adj     = (const float*)d_in[2];
    const float* label_w = (const float*)d_in[3];
    const int*   edges   = (const int*)d_in[4];
    float* out = (float*)d_out;

    // workspace layout (~13 MB; u64 array first for 8B alignment)
    ull*    part  = (ull*)d_ws;                                      // NQ*H*NC*8
    ushort* posb  = (ushort*)(part + (size_t)NQ * H * NC * KNBR);    // H*N*D bf16
    float*  pn2h  = (float*)(posb + (size_t)H * NN * D);             // H*N
    float*  knn_dd = (float*)(pn2h + (size_t)H * NN);                // NQ*H*8
    int*    knn_ii = (int*)(knn_dd + (size_t)NQ * H * KNBR);

    prep_pos<<<(NN * H + 255) / 256, 256, 0, stream>>>(pos, posb, pn2h);
    knn_mfma<<<dim3(NQ / 16, H, NC), 64, 0, stream>>>(posb, pn2h, edges, part);
    knn_merge<<<NQ * H, 64, 0, stream>>>(part, knn_dd, knn_ii);
    finalize<<<B, 64, 0, stream>>>(pos, grads, adj, label_w, edges, knn_dd, knn_ii, out);
}